// Round 1
// baseline (241.384 us; speedup 1.0000x reference)
//
#include <hip/hip_runtime.h>
#include <hip/hip_bf16.h>
#include <cstdint>
#include <cstddef>

// Sizes fixed by the reference problem.
#define DMODEL 1024
#define BATCH  4
#define SEQ    4096
#define BSROWS (BATCH*SEQ)     // 16384
#define CHUNK  32
#define NCHUNK (SEQ/CHUNK)     // 128

typedef __attribute__((ext_vector_type(8))) short bf16x8;
typedef __attribute__((ext_vector_type(4))) float f32x4;

// ---- helpers ---------------------------------------------------------------

__device__ __forceinline__ unsigned short f2bf(float f) {
  union { float f; uint32_t u; } v; v.f = f;
  uint32_t u = v.u;
  u += 0x7FFFu + ((u >> 16) & 1u);   // round-to-nearest-even
  return (unsigned short)(u >> 16);
}

__device__ __forceinline__ float sigmoid_dev(const float* dp) {
  return 1.0f / (1.0f + expf(-dp[0]));
}

typedef __attribute__((address_space(1))) void void_g;
typedef __attribute__((address_space(3))) void void_l;

__device__ __forceinline__ void gl2lds16(const void* g, void* l) {
  __builtin_amdgcn_global_load_lds((void_g*)g, (void_l*)l, 16, 0, 0);
}

// ---- weight prep -----------------------------------------------------------

// W_f (f32, [e][c]) -> bf16 [e][c]
__global__ void cast_wf_kernel(const float* __restrict__ src,
                               unsigned short* __restrict__ dst) {
  int i = blockIdx.x * 256 + threadIdx.x;   // over D*D/4 float4s
  float4 v = ((const float4*)src)[i];
  ushort4 o;
  o.x = f2bf(v.x); o.y = f2bf(v.y); o.z = f2bf(v.z); o.w = f2bf(v.w);
  ((ushort4*)dst)[i] = o;
}

// W_up (f32, [c][d]) -> bf16 transposed [d][c]
__global__ void trans_wup_kernel(const float* __restrict__ wup,
                                 unsigned short* __restrict__ out) {
  __shared__ float tile[32][33];
  int bx = blockIdx.x, by = blockIdx.y;
  int tx = threadIdx.x;
  int x = bx * 32 + tx;         // col (d) in wup
  int y0 = by * 32;             // row (c) base
  for (int j = threadIdx.y; j < 32; j += 8)
    tile[j][tx] = wup[(size_t)(y0 + j) * DMODEL + x];
  __syncthreads();
  int ox = by * 32 + tx;        // col (c) in out
  int oy0 = bx * 32;            // row (d) base
  for (int j = threadIdx.y; j < 32; j += 8)
    out[(size_t)(oy0 + j) * DMODEL + ox] = f2bf(tile[tx][j]);
}

// bb[e] = dot(W_f[e,:], b_up)   (f32)
__global__ void bb_kernel(const float* __restrict__ wf,
                          const float* __restrict__ bup,
                          float* __restrict__ bb) {
  int w = threadIdx.x >> 6;
  int lane = threadIdx.x & 63;
  int e = blockIdx.x * 4 + w;
  float s = 0.f;
  for (int i = lane; i < DMODEL; i += 64)
    s += wf[(size_t)e * DMODEL + i] * bup[i];
  #pragma unroll
  for (int off = 32; off; off >>= 1) s += __shfl_down(s, off);
  if (lane == 0) bb[e] = s;
}

// ---- scan (decay recurrence along s), chunked two-pass ---------------------

// Pass A: per (b, chunk) compute chunk carry (local scan final value, h0=0).
__global__ void scan_passA(const float* __restrict__ x,
                           const float* __restrict__ mask,
                           const float* __restrict__ dp,
                           float* __restrict__ carry,
                           float* __restrict__ carry_beta) {
  float decay = sigmoid_dev(dp);
  int b = blockIdx.x / NCHUNK, c = blockIdx.x % NCHUNK;
  int t = threadIdx.x;
  const float4* xp = (const float4*)(x + ((size_t)(b * SEQ + c * CHUNK)) * DMODEL);
  const float* mp = mask + b * SEQ + c * CHUNK;
  float4 h = make_float4(0.f, 0.f, 0.f, 0.f);
  float hb = 0.f;
  #pragma unroll 8
  for (int s = 0; s < CHUNK; ++s) {
    float m = mp[s];
    float4 xv = xp[(size_t)s * (DMODEL / 4) + t];
    h.x = decay * h.x + m * xv.x;
    h.y = decay * h.y + m * xv.y;
    h.z = decay * h.z + m * xv.z;
    h.w = decay * h.w + m * xv.w;
    hb = decay * hb + m;
  }
  ((float4*)carry)[(size_t)blockIdx.x * (DMODEL / 4) + t] = h;
  if (t == 0) carry_beta[blockIdx.x] = hb;
}

// Chunk-level exclusive scan: prefix[c] = h entering chunk c.
__global__ void scan_chunk(const float* __restrict__ carry,
                           const float* __restrict__ carry_beta,
                           const float* __restrict__ dp,
                           float* __restrict__ prefix,
                           float* __restrict__ prefix_beta) {
  float decay = sigmoid_dev(dp);
  float dL = powf(decay, (float)CHUNK);
  int gid = blockIdx.x * 256 + threadIdx.x;   // 0 .. BATCH*DMODEL-1
  int b = gid / DMODEL, d = gid % DMODEL;
  float P = 0.f;
  for (int c = 0; c < NCHUNK; ++c) {
    size_t idx = (size_t)(b * NCHUNK + c) * DMODEL + d;
    prefix[idx] = P;
    P = dL * P + carry[idx];
  }
  if (d == 0) {
    float Pb = 0.f;
    for (int c = 0; c < NCHUNK; ++c) {
      prefix_beta[b * NCHUNK + c] = Pb;
      Pb = dL * Pb + carry_beta[b * NCHUNK + c];
    }
  }
}

// Pass C: re-run local scan seeded by prefix; emit hv (bf16) and hbeta (f32).
__global__ void scan_passC(const float* __restrict__ x,
                           const float* __restrict__ mask,
                           const float* __restrict__ dp,
                           const float* __restrict__ prefix,
                           const float* __restrict__ prefix_beta,
                           unsigned short* __restrict__ hv,
                           float* __restrict__ hbeta) {
  float decay = sigmoid_dev(dp);
  int b = blockIdx.x / NCHUNK, c = blockIdx.x % NCHUNK;
  int t = threadIdx.x;
  const float4* xp = (const float4*)(x + ((size_t)(b * SEQ + c * CHUNK)) * DMODEL);
  const float* mp = mask + b * SEQ + c * CHUNK;
  float4 h = ((const float4*)prefix)[(size_t)blockIdx.x * (DMODEL / 4) + t];
  float hb = prefix_beta[blockIdx.x];
  #pragma unroll 8
  for (int s = 0; s < CHUNK; ++s) {
    float m = mp[s];
    float4 xv = xp[(size_t)s * (DMODEL / 4) + t];
    h.x = decay * h.x + m * xv.x;
    h.y = decay * h.y + m * xv.y;
    h.z = decay * h.z + m * xv.z;
    h.w = decay * h.w + m * xv.w;
    hb = decay * hb + m;
    ushort4 o;
    o.x = f2bf(h.x); o.y = f2bf(h.y); o.z = f2bf(h.z); o.w = f2bf(h.w);
    int row = b * SEQ + c * CHUNK + s;
    ((ushort4*)hv)[(size_t)row * (DMODEL / 4) + t] = o;
    if (t == 0) hbeta[row] = hb;
  }
}

// ---- MFMA NT GEMMs (m97 structure: 128x128 tile, BK=32, global_load_lds) ---

// Wc[e][d] = sum_c Wf_bf[e][c] * WupT_bf[d][c]   (bf16 out)
__global__ __launch_bounds__(256) void gemm_wc(
    const unsigned short* __restrict__ A,    // [1024][1024] rows=e
    const unsigned short* __restrict__ Bm,   // [1024][1024] rows=d
    unsigned short* __restrict__ out) {      // [e][d]
  __shared__ unsigned short As[128 * 32];
  __shared__ unsigned short Bs[128 * 32];
  int tid = threadIdx.x;
  int lane = tid & 63, w = tid >> 6;
  int wm = w & 1, wn = w >> 1;
  int m0 = (blockIdx.x >> 3) * 128;
  int n0 = (blockIdx.x & 7) * 128;
  int r = tid >> 2;
  int c8 = (tid & 3) * 8;
  f32x4 acc[4][4] = {};
  for (int k0 = 0; k0 < DMODEL; k0 += 32) {
    gl2lds16(A + (size_t)(m0 + r) * DMODEL + k0 + c8,        As + r * 32 + c8);
    gl2lds16(A + (size_t)(m0 + 64 + r) * DMODEL + k0 + c8,   As + (64 + r) * 32 + c8);
    gl2lds16(Bm + (size_t)(n0 + r) * DMODEL + k0 + c8,       Bs + r * 32 + c8);
    gl2lds16(Bm + (size_t)(n0 + 64 + r) * DMODEL + k0 + c8,  Bs + (64 + r) * 32 + c8);
    __syncthreads();
    const bf16x8* Av = (const bf16x8*)As;
    const bf16x8* Bv = (const bf16x8*)Bs;
    int quad = lane >> 4, l16 = lane & 15;
    bf16x8 af[4], bfr[4];
    #pragma unroll
    for (int i = 0; i < 4; i++) {
      af[i]  = Av[(wm * 64 + i * 16 + l16) * 4 + quad];
      bfr[i] = Bv[(wn * 64 + i * 16 + l16) * 4 + quad];
    }
    #pragma unroll
    for (int i = 0; i < 4; i++)
      #pragma unroll
      for (int j = 0; j < 4; j++)
        acc[i][j] = __builtin_amdgcn_mfma_f32_16x16x32_bf16(af[i], bfr[j], acc[i][j], 0, 0, 0);
    __syncthreads();
  }
  int quad = lane >> 4, l16 = lane & 15;
  #pragma unroll
  for (int j = 0; j < 4; j++) {
    int col = n0 + wn * 64 + j * 16 + l16;
    #pragma unroll
    for (int i = 0; i < 4; i++) {
      int rowb = m0 + wm * 64 + i * 16 + quad * 4;
      #pragma unroll
      for (int rr = 0; rr < 4; ++rr)
        out[(size_t)(rowb + rr) * DMODEL + col] = f2bf(acc[i][j][rr]);
    }
  }
}

// out[t][e] = sum_d hv[t][d]*Wc[e][d] + hbeta[t]*bb[e] + b_f[e]   (f32 out)
__global__ __launch_bounds__(256) void gemm_main(
    const unsigned short* __restrict__ A,    // hv bf16 [16384][1024]
    const unsigned short* __restrict__ Bm,   // Wc bf16 [1024][1024] rows=e
    const float* __restrict__ hbeta,
    const float* __restrict__ bb,
    const float* __restrict__ bias_f,
    float* __restrict__ out) {
  __shared__ unsigned short As[128 * 32];
  __shared__ unsigned short Bs[128 * 32];
  int tid = threadIdx.x;
  int lane = tid & 63, w = tid >> 6;
  int wm = w & 1, wn = w >> 1;
  int m0 = (blockIdx.x >> 3) * 128;   // 128 m-tiles
  int n0 = (blockIdx.x & 7) * 128;    // 8 n-tiles
  int r = tid >> 2;
  int c8 = (tid & 3) * 8;
  f32x4 acc[4][4] = {};
  for (int k0 = 0; k0 < DMODEL; k0 += 32) {
    gl2lds16(A + (size_t)(m0 + r) * DMODEL + k0 + c8,        As + r * 32 + c8);
    gl2lds16(A + (size_t)(m0 + 64 + r) * DMODEL + k0 + c8,   As + (64 + r) * 32 + c8);
    gl2lds16(Bm + (size_t)(n0 + r) * DMODEL + k0 + c8,       Bs + r * 32 + c8);
    gl2lds16(Bm + (size_t)(n0 + 64 + r) * DMODEL + k0 + c8,  Bs + (64 + r) * 32 + c8);
    __syncthreads();
    const bf16x8* Av = (const bf16x8*)As;
    const bf16x8* Bv = (const bf16x8*)Bs;
    int quad = lane >> 4, l16 = lane & 15;
    bf16x8 af[4], bfr[4];
    #pragma unroll
    for (int i = 0; i < 4; i++) {
      af[i]  = Av[(wm * 64 + i * 16 + l16) * 4 + quad];
      bfr[i] = Bv[(wn * 64 + i * 16 + l16) * 4 + quad];
    }
    #pragma unroll
    for (int i = 0; i < 4; i++)
      #pragma unroll
      for (int j = 0; j < 4; j++)
        acc[i][j] = __builtin_amdgcn_mfma_f32_16x16x32_bf16(af[i], bfr[j], acc[i][j], 0, 0, 0);
    __syncthreads();
  }
  int quad = lane >> 4, l16 = lane & 15;
  #pragma unroll
  for (int j = 0; j < 4; j++) {
    int col = n0 + wn * 64 + j * 16 + l16;
    float bbv = bb[col];
    float bfv = bias_f[col];
    #pragma unroll
    for (int i = 0; i < 4; i++) {
      int rowb = m0 + wm * 64 + i * 16 + quad * 4;
      #pragma unroll
      for (int rr = 0; rr < 4; ++rr) {
        int row = rowb + rr;
        out[(size_t)row * DMODEL + col] = acc[i][j][rr] + hbeta[row] * bbv + bfv;
      }
    }
  }
}

// ---- launch ----------------------------------------------------------------

extern "C" void kernel_launch(void* const* d_in, const int* in_sizes, int n_in,
                              void* d_out, int out_size, void* d_ws, size_t ws_size,
                              hipStream_t stream) {
  const float* x    = (const float*)d_in[0];
  const float* mask = (const float*)d_in[1];
  const float* W_up = (const float*)d_in[2];
  const float* b_up = (const float*)d_in[3];
  const float* W_f  = (const float*)d_in[4];
  const float* b_f  = (const float*)d_in[5];
  const float* dp   = (const float*)d_in[6];
  float* out = (float*)d_out;

  char* ws = (char*)d_ws;
  unsigned short* hv    = (unsigned short*)(ws);                 // 32 MB
  unsigned short* Wc    = (unsigned short*)(ws + 33554432);      // 2 MB
  unsigned short* Wf_bf = (unsigned short*)(ws + 35651584);      // 2 MB
  unsigned short* WupT  = (unsigned short*)(ws + 37748736);      // 2 MB
  float* carry  = (float*)(ws + 39845888);                       // 2 MB
  float* prefix = (float*)(ws + 41943040);                       // 2 MB
  float* hbeta  = (float*)(ws + 44040192);                       // 64 KB
  float* cbeta  = (float*)(ws + 44105728);                       // 2 KB
  float* pbeta  = (float*)(ws + 44107776);                       // 2 KB
  float* bb     = (float*)(ws + 44109824);                       // 4 KB

  cast_wf_kernel<<<1024, 256, 0, stream>>>(W_f, Wf_bf);
  trans_wup_kernel<<<dim3(32, 32), dim3(32, 8), 0, stream>>>(W_up, WupT);
  bb_kernel<<<256, 256, 0, stream>>>(W_f, b_up, bb);
  gemm_wc<<<64, 256, 0, stream>>>(Wf_bf, WupT, Wc);
  scan_passA<<<BATCH * NCHUNK, 256, 0, stream>>>(x, mask, dp, carry, cbeta);
  scan_chunk<<<16, 256, 0, stream>>>(carry, cbeta, dp, prefix, pbeta);
  scan_passC<<<BATCH * NCHUNK, 256, 0, stream>>>(x, mask, dp, prefix, pbeta, hv, hbeta);
  gemm_main<<<1024, 256, 0, stream>>>(hv, Wc, hbeta, bb, b_f, out);
}

// Round 2
// 203.765 us; speedup vs baseline: 1.1846x; 1.1846x over previous
//
#include <hip/hip_runtime.h>
#include <hip/hip_bf16.h>
#include <cstdint>
#include <cstddef>

// Sizes fixed by the reference problem.
#define DMODEL 1024
#define BATCH  4
#define SEQ    4096
#define BSROWS (BATCH*SEQ)     // 16384
#define CHUNK  32
#define NCHUNK (SEQ/CHUNK)     // 128

typedef __attribute__((ext_vector_type(8))) short bf16x8;
typedef __attribute__((ext_vector_type(4))) float f32x4;

// ---- helpers ---------------------------------------------------------------

__device__ __forceinline__ unsigned short f2bf(float f) {
  union { float f; uint32_t u; } v; v.f = f;
  uint32_t u = v.u;
  u += 0x7FFFu + ((u >> 16) & 1u);   // round-to-nearest-even
  return (unsigned short)(u >> 16);
}

__device__ __forceinline__ float sigmoid_dev(const float* dp) {
  return 1.0f / (1.0f + expf(-dp[0]));
}

typedef __attribute__((address_space(1))) void void_g;
typedef __attribute__((address_space(3))) void void_l;

__device__ __forceinline__ void gl2lds16(const void* g, void* l) {
  __builtin_amdgcn_global_load_lds((void_g*)g, (void_l*)l, 16, 0, 0);
}

// ---- fused prep: scan_passA + cast W_f + transpose W_up + bb ---------------
// blocks [0,512)    : scan pass A (per (b,chunk) carry)
// blocks [512,1536) : W_f f32 -> bf16
// blocks [1536,2560): W_up f32 [c][d] -> bf16 transposed [d][c]
// blocks [2560,2816): bb[e] = dot(W_f[e,:], b_up)
__global__ __launch_bounds__(256) void prep_kernel(
    const float* __restrict__ x, const float* __restrict__ mask,
    const float* __restrict__ W_up, const float* __restrict__ b_up,
    const float* __restrict__ W_f, const float* __restrict__ dp,
    unsigned short* __restrict__ Wf_bf, unsigned short* __restrict__ WupT,
    float* __restrict__ bb, float* __restrict__ carry,
    float* __restrict__ cbeta) {
  __shared__ float tile[32][33];
  int blk = blockIdx.x;
  int tid = threadIdx.x;

  if (blk < 512) {
    // ---- scan pass A ----
    float decay = sigmoid_dev(dp);
    int b = blk / NCHUNK, c = blk % NCHUNK;
    const float4* xp = (const float4*)(x + ((size_t)(b * SEQ + c * CHUNK)) * DMODEL);
    const float* mp = mask + b * SEQ + c * CHUNK;
    float4 h = make_float4(0.f, 0.f, 0.f, 0.f);
    float hb = 0.f;
    #pragma unroll 8
    for (int s = 0; s < CHUNK; ++s) {
      float m = mp[s];
      float4 xv = xp[(size_t)s * (DMODEL / 4) + tid];
      h.x = decay * h.x + m * xv.x;
      h.y = decay * h.y + m * xv.y;
      h.z = decay * h.z + m * xv.z;
      h.w = decay * h.w + m * xv.w;
      hb = decay * hb + m;
    }
    ((float4*)carry)[(size_t)blk * (DMODEL / 4) + tid] = h;
    if (tid == 0) cbeta[blk] = hb;
  } else if (blk < 1536) {
    // ---- cast W_f ----
    int i = (blk - 512) * 256 + tid;     // over D*D/4 float4s
    float4 v = ((const float4*)W_f)[i];
    ushort4 o;
    o.x = f2bf(v.x); o.y = f2bf(v.y); o.z = f2bf(v.z); o.w = f2bf(v.w);
    ((ushort4*)Wf_bf)[i] = o;
  } else if (blk < 2560) {
    // ---- transpose+cast W_up ----
    int id = blk - 1536;
    int bx = id & 31, by = id >> 5;
    int tx = tid & 31, ty = tid >> 5;   // 32 x 8
    int xx = bx * 32 + tx;
    int y0 = by * 32;
    for (int j = ty; j < 32; j += 8)
      tile[j][tx] = W_up[(size_t)(y0 + j) * DMODEL + xx];
    __syncthreads();
    int ox = by * 32 + tx;
    int oy0 = bx * 32;
    for (int j = ty; j < 32; j += 8)
      WupT[(size_t)(oy0 + j) * DMODEL + ox] = f2bf(tile[tx][j]);
  } else {
    // ---- bb ----
    int w = tid >> 6;
    int lane = tid & 63;
    int e = (blk - 2560) * 4 + w;
    float s = 0.f;
    for (int i = lane; i < DMODEL; i += 64)
      s += W_f[(size_t)e * DMODEL + i] * b_up[i];
    #pragma unroll
    for (int off = 32; off; off >>= 1) s += __shfl_down(s, off);
    if (lane == 0) bb[e] = s;
  }
}

// ---- chunk-level exclusive scan (grid 64 x block 64) -----------------------
__global__ __launch_bounds__(64) void scan_chunk(
    const float* __restrict__ carry, const float* __restrict__ carry_beta,
    const float* __restrict__ dp, float* __restrict__ prefix,
    float* __restrict__ prefix_beta) {
  float decay = sigmoid_dev(dp);
  float dL = powf(decay, (float)CHUNK);
  int gid = blockIdx.x * 64 + threadIdx.x;   // 0 .. BATCH*DMODEL-1
  int b = gid >> 10, d = gid & 1023;
  float P = 0.f;
  for (int c = 0; c < NCHUNK; c += 8) {
    float v[8];
    #pragma unroll
    for (int j = 0; j < 8; ++j)
      v[j] = carry[(size_t)(b * NCHUNK + c + j) * DMODEL + d];
    #pragma unroll
    for (int j = 0; j < 8; ++j) {
      prefix[(size_t)(b * NCHUNK + c + j) * DMODEL + d] = P;
      P = dL * P + v[j];
    }
  }
  if (d == 0) {
    float Pb = 0.f;
    for (int c = 0; c < NCHUNK; ++c) {
      prefix_beta[b * NCHUNK + c] = Pb;
      Pb = dL * Pb + carry_beta[b * NCHUNK + c];
    }
  }
}

// ---- fused mid: gemm_wc (64x64 tiles, 256 blocks) + scan pass C (512) ------
__global__ __launch_bounds__(256) void mid_kernel(
    const unsigned short* __restrict__ A,    // Wf_bf [1024][1024] rows=e
    const unsigned short* __restrict__ Bm,   // WupT  [1024][1024] rows=d
    unsigned short* __restrict__ Wc,         // out [e][d] bf16
    const float* __restrict__ x, const float* __restrict__ mask,
    const float* __restrict__ dp,
    const float* __restrict__ prefix, const float* __restrict__ prefix_beta,
    unsigned short* __restrict__ hv, float* __restrict__ hbeta) {
  __shared__ unsigned short As[64 * 32];
  __shared__ unsigned short Bs[64 * 32];
  int tid = threadIdx.x;
  if (blockIdx.x < 256) {
    // ---- Wc = W_f @ W_up  (NT, 64x64 tile) ----
    int vb = blockIdx.x;
    int lane = tid & 63, w = tid >> 6;
    int wm = w & 1, wn = w >> 1;
    int m0 = (vb >> 4) * 64;
    int n0 = (vb & 15) * 64;
    int r = tid >> 2;            // 0..63
    int c8 = (tid & 3) * 8;
    f32x4 acc[2][2] = {};
    for (int k0 = 0; k0 < DMODEL; k0 += 32) {
      gl2lds16(A + (size_t)(m0 + r) * DMODEL + k0 + c8,  As + r * 32 + c8);
      gl2lds16(Bm + (size_t)(n0 + r) * DMODEL + k0 + c8, Bs + r * 32 + c8);
      __syncthreads();
      const bf16x8* Av = (const bf16x8*)As;
      const bf16x8* Bv = (const bf16x8*)Bs;
      int quad = lane >> 4, l16 = lane & 15;
      bf16x8 af[2], bfr[2];
      #pragma unroll
      for (int i = 0; i < 2; i++) {
        af[i]  = Av[(wm * 32 + i * 16 + l16) * 4 + quad];
        bfr[i] = Bv[(wn * 32 + i * 16 + l16) * 4 + quad];
      }
      #pragma unroll
      for (int i = 0; i < 2; i++)
        #pragma unroll
        for (int j = 0; j < 2; j++)
          acc[i][j] = __builtin_amdgcn_mfma_f32_16x16x32_bf16(af[i], bfr[j], acc[i][j], 0, 0, 0);
      __syncthreads();
    }
    int quad = lane >> 4, l16 = lane & 15;
    #pragma unroll
    for (int j = 0; j < 2; j++) {
      int col = n0 + wn * 32 + j * 16 + l16;
      #pragma unroll
      for (int i = 0; i < 2; i++) {
        int rowb = m0 + wm * 32 + i * 16 + quad * 4;
        #pragma unroll
        for (int rr = 0; rr < 4; ++rr)
          Wc[(size_t)(rowb + rr) * DMODEL + col] = f2bf(acc[i][j][rr]);
      }
    }
  } else {
    // ---- scan pass C: seeded local scan, emit hv(bf16) + hbeta(f32) ----
    int vb = blockIdx.x - 256;
    float decay = sigmoid_dev(dp);
    int b = vb / NCHUNK, c = vb % NCHUNK;
    const float4* xp = (const float4*)(x + ((size_t)(b * SEQ + c * CHUNK)) * DMODEL);
    const float* mp = mask + b * SEQ + c * CHUNK;
    float4 h = ((const float4*)prefix)[(size_t)vb * (DMODEL / 4) + tid];
    float hb = prefix_beta[vb];
    #pragma unroll 8
    for (int s = 0; s < CHUNK; ++s) {
      float m = mp[s];
      float4 xv = xp[(size_t)s * (DMODEL / 4) + tid];
      h.x = decay * h.x + m * xv.x;
      h.y = decay * h.y + m * xv.y;
      h.z = decay * h.z + m * xv.z;
      h.w = decay * h.w + m * xv.w;
      hb = decay * hb + m;
      ushort4 o;
      o.x = f2bf(h.x); o.y = f2bf(h.y); o.z = f2bf(h.z); o.w = f2bf(h.w);
      int row = b * SEQ + c * CHUNK + s;
      ((ushort4*)hv)[(size_t)row * (DMODEL / 4) + tid] = o;
      if (tid == 0) hbeta[row] = hb;
    }
  }
}

// ---- main GEMM: out = hv @ Wc^T + hbeta*bb + b_f  (m97 structure) ----------
// XCD swizzle: mt = blk&127 so the 8 blocks sharing an A (hv) tile all land
// on the same XCD (round-robin blk%8) -> A tile stays in that XCD's L2.
__global__ __launch_bounds__(256) void gemm_main(
    const unsigned short* __restrict__ A,    // hv bf16 [16384][1024]
    const unsigned short* __restrict__ Bm,   // Wc bf16 [1024][1024] rows=e
    const float* __restrict__ hbeta,
    const float* __restrict__ bb,
    const float* __restrict__ bias_f,
    float* __restrict__ out) {
  __shared__ unsigned short As[128 * 32];
  __shared__ unsigned short Bs[128 * 32];
  int tid = threadIdx.x;
  int lane = tid & 63, w = tid >> 6;
  int wm = w & 1, wn = w >> 1;
  int m0 = (blockIdx.x & 127) * 128;   // 128 m-tiles, consecutive blk -> same XCD gets same m set
  int n0 = (blockIdx.x >> 7) * 128;    // 8 n-tiles
  int r = tid >> 2;
  int c8 = (tid & 3) * 8;
  f32x4 acc[4][4] = {};
  for (int k0 = 0; k0 < DMODEL; k0 += 32) {
    gl2lds16(A + (size_t)(m0 + r) * DMODEL + k0 + c8,        As + r * 32 + c8);
    gl2lds16(A + (size_t)(m0 + 64 + r) * DMODEL + k0 + c8,   As + (64 + r) * 32 + c8);
    gl2lds16(Bm + (size_t)(n0 + r) * DMODEL + k0 + c8,       Bs + r * 32 + c8);
    gl2lds16(Bm + (size_t)(n0 + 64 + r) * DMODEL + k0 + c8,  Bs + (64 + r) * 32 + c8);
    __syncthreads();
    const bf16x8* Av = (const bf16x8*)As;
    const bf16x8* Bv = (const bf16x8*)Bs;
    int quad = lane >> 4, l16 = lane & 15;
    bf16x8 af[4], bfr[4];
    #pragma unroll
    for (int i = 0; i < 4; i++) {
      af[i]  = Av[(wm * 64 + i * 16 + l16) * 4 + quad];
      bfr[i] = Bv[(wn * 64 + i * 16 + l16) * 4 + quad];
    }
    #pragma unroll
    for (int i = 0; i < 4; i++)
      #pragma unroll
      for (int j = 0; j < 4; j++)
        acc[i][j] = __builtin_amdgcn_mfma_f32_16x16x32_bf16(af[i], bfr[j], acc[i][j], 0, 0, 0);
    __syncthreads();
  }
  int quad = lane >> 4, l16 = lane & 15;
  #pragma unroll
  for (int j = 0; j < 4; j++) {
    int col = n0 + wn * 64 + j * 16 + l16;
    float bbv = bb[col];
    float bfv = bias_f[col];
    #pragma unroll
    for (int i = 0; i < 4; i++) {
      int rowb = m0 + wm * 64 + i * 16 + quad * 4;
      #pragma unroll
      for (int rr = 0; rr < 4; ++rr) {
        int row = rowb + rr;
        out[(size_t)row * DMODEL + col] = acc[i][j][rr] + hbeta[row] * bbv + bfv;
      }
    }
  }
}

// ---- launch ----------------------------------------------------------------

extern "C" void kernel_launch(void* const* d_in, const int* in_sizes, int n_in,
                              void* d_out, int out_size, void* d_ws, size_t ws_size,
                              hipStream_t stream) {
  const float* x    = (const float*)d_in[0];
  const float* mask = (const float*)d_in[1];
  const float* W_up = (const float*)d_in[2];
  const float* b_up = (const float*)d_in[3];
  const float* W_f  = (const float*)d_in[4];
  const float* b_f  = (const float*)d_in[5];
  const float* dp   = (const float*)d_in[6];
  float* out = (float*)d_out;

  char* ws = (char*)d_ws;
  unsigned short* hv    = (unsigned short*)(ws);                 // 32 MB
  unsigned short* Wc    = (unsigned short*)(ws + 33554432);      // 2 MB
  unsigned short* Wf_bf = (unsigned short*)(ws + 35651584);      // 2 MB
  unsigned short* WupT  = (unsigned short*)(ws + 37748736);      // 2 MB
  float* carry  = (float*)(ws + 39845888);                       // 2 MB
  float* prefix = (float*)(ws + 41943040);                       // 2 MB
  float* hbeta  = (float*)(ws + 44040192);                       // 64 KB
  float* cbeta  = (float*)(ws + 44105728);                       // 2 KB
  float* pbeta  = (float*)(ws + 44107776);                       // 2 KB
  float* bb     = (float*)(ws + 44109824);                       // 4 KB

  prep_kernel<<<2816, 256, 0, stream>>>(x, mask, W_up, b_up, W_f, dp,
                                        Wf_bf, WupT, bb, carry, cbeta);
  scan_chunk<<<64, 64, 0, stream>>>(carry, cbeta, dp, prefix, pbeta);
  mid_kernel<<<768, 256, 0, stream>>>(Wf_bf, WupT, Wc, x, mask, dp,
                                      prefix, pbeta, hv, hbeta);
  gemm_main<<<1024, 256, 0, stream>>>(hv, Wc, hbeta, bb, b_f, out);
}